// Round 1
// baseline (5118.171 us; speedup 1.0000x reference)
//
#include <hip/hip_runtime.h>
#include <cstdint>

// ODEBlock: 16 RK4 steps of f(t,y) = tanh(y@W1 + b1 + t) @ W2 + b2
// B=1024 (M), D=512, H=2048. bf16 MFMA GEMMs, fp32 state/epilogues.
// R14: fuse each f-eval (gemm1 -> gemm2 -> RK4 combine) into ONE kernel.
//  - NOT grid-sync (R3/R6/R9 showed cooperative sync is ~10us+/sync): uses
//    tile-local release/acquire counters. Consumer group == producer group
//    (8 aligned consecutive blocks) -> deadlock-free with any >=8 resident.
//  - split-K=4 combine: last-arriving block (atomic counter old==3) does the
//    RK4 epilogue for its 64x64 tile. No spin in that phase at all.
//  - W2T B-tile staged BEFORE the spin (no dependency) to hide latency.
//  - gemm cores identical to R11 best (64x64 tiles, BK=128, XOR-swizzled
//    LDS staging, 64KB dbuf, 2 blocks/CU).
// Dispatches: 195 -> 68 (2 transpose + init + 64 fused).

typedef __bf16 bf16x8 __attribute__((ext_vector_type(8)));
typedef float f32x4 __attribute__((ext_vector_type(4)));

#define AS1 __attribute__((address_space(1)))
#define AS3 __attribute__((address_space(3)))

#define MDIM 1024
#define DDIM 512
#define HDIM 2048

#define GEMM_LDS (64 * 1024)   // sA 2x16KB + sB 2x16KB

__device__ __forceinline__ void async_copy16(const void* g, void* lds) {
  __builtin_amdgcn_global_load_lds((const AS1 void*)g, (AS3 void*)lds, 16, 0, 0);
}

__device__ __forceinline__ unsigned short f32_to_bf16(float f) {
  union { float f; unsigned u; } c; c.f = f;
  unsigned u = c.u + 0x7FFFu + ((c.u >> 16) & 1u);   // RNE
  return (unsigned short)(u >> 16);
}

__device__ __forceinline__ float bf16_to_f32(unsigned short h) {
  union { unsigned u; float f; } c; c.u = ((unsigned)h) << 16;
  return c.f;
}

__device__ __forceinline__ float tanh_fast(float x) {
  float a = __builtin_fabsf(x);
  float e = __expf(-2.0f * a);                        // in (0,1], no overflow
  float r = (1.0f - e) * __builtin_amdgcn_rcpf(1.0f + e);
  return __builtin_copysignf(r, x);
}

// ---- transpose + f32->bf16: out[c*R + r] = bf16(in[r*C + c]) --------------
__global__ __launch_bounds__(256) void transpose_bf16_kernel(
    const float* __restrict__ in, unsigned short* __restrict__ out, int R, int C) {
  __shared__ float tile[64][65];
  int nbc = C >> 6;
  int br = blockIdx.x / nbc, bc = blockIdx.x % nbc;
  int r0 = br * 64, c0 = bc * 64;
  int tr = threadIdx.x >> 6, tc = threadIdx.x & 63;
  for (int i = 0; i < 16; ++i) {
    int row = i * 4 + tr;
    tile[row][tc] = in[(r0 + row) * C + c0 + tc];
  }
  __syncthreads();
  for (int i = 0; i < 16; ++i) {
    int row = i * 4 + tr;
    out[(c0 + row) * R + r0 + tc] = f32_to_bf16(tile[tc][row]);
  }
}

// ---- init: y = x (fp32, lives in d_out), arg = bf16(x), zero counters -----
__global__ __launch_bounds__(256) void init_kernel(
    const float* __restrict__ x, float* __restrict__ y,
    unsigned short* __restrict__ arg, int* __restrict__ cnts) {
  int i = blockIdx.x * 256 + threadIdx.x;
  float v = x[i];
  y[i] = v;
  arg[i] = f32_to_bf16(v);
  if (i < 64 * 192) cnts[i] = 0;      // 64 evals x (64 panel + 128 tile) counters
}

// ---- fused eval: gemm1 -> (tile-local sync) -> gemm2 split-K -> RK4 -------
// Producer tile:  bm1=bid>>5, bn1=bid&31 -> increments cnt[bid>>3] (release)
// Consumer tile:  bm2=bid>>5, s=(bid>>3)&3, bn2=bid&7 -> waits cnt[bid>>3]==8
//   (its own aligned 8-block group: deadlock-free without full co-residency)
// Combine: cnt[64 + bm2*8 + bn2] fetch_add; old==3 block does RK4 epilogue.
__global__ __launch_bounds__(256, 2) void fused_eval_kernel(
    unsigned short* __restrict__ arg,        // [1024,512] bf16 in+out (safe, see proof in notes)
    const unsigned short* __restrict__ W1T,  // [2048,512] bf16
    const float* __restrict__ b1,
    const unsigned short* __restrict__ W2T,  // [512,2048] bf16
    unsigned short* __restrict__ Hbuf,       // [1024,2048] bf16
    unsigned short* __restrict__ part,       // [4][1024,512] bf16
    const float* __restrict__ b2,
    float* __restrict__ y, float* __restrict__ kacc,
    int* __restrict__ cnt,                   // this eval's 192 counters (pre-zeroed)
    float tval, int mode, float dt)
{
  extern __shared__ char ldsbuf[];
  bf16x8* sA = (bf16x8*)ldsbuf;              // 2 x 1024 units (32KB)
  bf16x8* sB = (bf16x8*)(ldsbuf + 32768);    // 2 x 1024 units (32KB)
  int bid = blockIdx.x;
  int tid = threadIdx.x;
  int lane = tid & 63;
  int wid = tid >> 6;
  int l15 = lane & 15;
  int l4 = lane >> 4;
  int wm = (wid >> 1) * 32;
  int wn = (wid & 1) * 32;
  int sw = l15 & 7;                          // read-side swizzle (row & 7)

  // ================= Phase A: gemm1 tile =================
  int bm1 = bid >> 5, bn1 = bid & 31;
  {
    const unsigned short* gA[4];
    const unsigned short* gB[4];
#pragma unroll
    for (int i = 0; i < 4; ++i) {
      int u = tid + i * 256, r = u >> 4, sl = u & 15;
      int koff = (sl ^ (r & 7)) * 8;
      gA[i] = arg + (size_t)(bm1 * 64 + r) * DDIM + koff;
      gB[i] = W1T + (size_t)(bn1 * 64 + r) * DDIM + koff;
    }
    f32x4 acc[2][2] = {};
#pragma unroll
    for (int i = 0; i < 4; ++i) {
      async_copy16(gA[i], &sA[tid + i * 256]);
      async_copy16(gB[i], &sB[tid + i * 256]);
    }
#pragma unroll 1
    for (int kt = 0; kt < 4; ++kt) {
      int cur = kt & 1;
      __syncthreads();
      if (kt + 1 < 4) {
        int nxt = cur ^ 1, off = (kt + 1) * 128;
#pragma unroll
        for (int i = 0; i < 4; ++i) {
          async_copy16(gA[i] + off, &sA[nxt * 1024 + tid + i * 256]);
          async_copy16(gB[i] + off, &sB[nxt * 1024 + tid + i * 256]);
        }
      }
#pragma unroll
      for (int ks = 0; ks < 4; ++ks) {
        int kg = (ks * 4 + l4) ^ sw;
        bf16x8 af[2], bfr[2];
#pragma unroll
        for (int i = 0; i < 2; ++i)
          af[i] = sA[cur * 1024 + (wm + i * 16 + l15) * 16 + kg];
#pragma unroll
        for (int j = 0; j < 2; ++j)
          bfr[j] = sB[cur * 1024 + (wn + j * 16 + l15) * 16 + kg];
#pragma unroll
        for (int i = 0; i < 2; ++i)
#pragma unroll
          for (int j = 0; j < 2; ++j)
            acc[i][j] = __builtin_amdgcn_mfma_f32_16x16x32_bf16(
                af[i], bfr[j], acc[i][j], 0, 0, 0);
      }
    }
    int row0 = bm1 * 64 + wm + l4 * 4;
    int col0 = bn1 * 64 + wn + l15;
    float bias[2];
#pragma unroll
    for (int j = 0; j < 2; ++j) bias[j] = b1[col0 + j * 16] + tval;
#pragma unroll
    for (int i = 0; i < 2; ++i)
#pragma unroll
      for (int r = 0; r < 4; ++r) {
        unsigned short* Hrow = Hbuf + (size_t)(row0 + i * 16 + r) * HDIM + col0;
#pragma unroll
        for (int j = 0; j < 2; ++j)
          Hrow[j * 16] = f32_to_bf16(tanh_fast(acc[i][j][r] + bias[j]));
      }
  }

  // ================= handoff: release H panel, wait for our group ========
  int bm2 = bid >> 5, s = (bid >> 3) & 3, bn2 = bid & 7;
  int g = bid >> 3;                          // shared producer/consumer counter
  const unsigned short* gA2[4];
  const unsigned short* gB2[4];
#pragma unroll
  for (int i = 0; i < 4; ++i) {
    int u = tid + i * 256, r = u >> 4, sl = u & 15;
    int koff = (sl ^ (r & 7)) * 8;
    gA2[i] = Hbuf + (size_t)(bm2 * 64 + r) * HDIM + s * 512 + koff;
    gB2[i] = W2T + (size_t)(bn2 * 64 + r) * HDIM + s * 512 + koff;
  }
  __syncthreads();   // drains H stores (vmcnt0) + all LDS reads complete
  if (tid == 0)
    __hip_atomic_fetch_add(&cnt[g], 1, __ATOMIC_RELEASE, __HIP_MEMORY_SCOPE_AGENT);
  // prefetch gemm2 B-tile (static weights, no dependency) under the wait
#pragma unroll
  for (int i = 0; i < 4; ++i) async_copy16(gB2[i], &sB[tid + i * 256]);
  if (tid == 0) {
    while (__hip_atomic_load(&cnt[g], __ATOMIC_RELAXED, __HIP_MEMORY_SCOPE_AGENT) < 8)
      __builtin_amdgcn_s_sleep(2);
  }
  __syncthreads();
  (void)__hip_atomic_load(&cnt[g], __ATOMIC_ACQUIRE, __HIP_MEMORY_SCOPE_AGENT);
#pragma unroll
  for (int i = 0; i < 4; ++i) async_copy16(gA2[i], &sA[tid + i * 256]);

  // ================= Phase B: gemm2 split-K tile =================
  {
    f32x4 acc[2][2] = {};
#pragma unroll 1
    for (int kt = 0; kt < 4; ++kt) {
      int cur = kt & 1;
      __syncthreads();
      if (kt + 1 < 4) {
        int nxt = cur ^ 1, off = (kt + 1) * 128;
#pragma unroll
        for (int i = 0; i < 4; ++i) {
          async_copy16(gA2[i] + off, &sA[nxt * 1024 + tid + i * 256]);
          async_copy16(gB2[i] + off, &sB[nxt * 1024 + tid + i * 256]);
        }
      }
#pragma unroll
      for (int ks = 0; ks < 4; ++ks) {
        int kg = (ks * 4 + l4) ^ sw;
        bf16x8 af[2], bfr[2];
#pragma unroll
        for (int i = 0; i < 2; ++i)
          af[i] = sA[cur * 1024 + (wm + i * 16 + l15) * 16 + kg];
#pragma unroll
        for (int j = 0; j < 2; ++j)
          bfr[j] = sB[cur * 1024 + (wn + j * 16 + l15) * 16 + kg];
#pragma unroll
        for (int i = 0; i < 2; ++i)
#pragma unroll
          for (int j = 0; j < 2; ++j)
            acc[i][j] = __builtin_amdgcn_mfma_f32_16x16x32_bf16(
                af[i], bfr[j], acc[i][j], 0, 0, 0);
      }
    }
    int row0 = bm2 * 64 + wm + l4 * 4;
    int col0 = bn2 * 64 + wn + l15;
    unsigned short* P = part + (size_t)s * (MDIM * DDIM);
#pragma unroll
    for (int i = 0; i < 2; ++i)
#pragma unroll
      for (int r = 0; r < 4; ++r) {
        unsigned short* Prow = P + (size_t)(row0 + i * 16 + r) * DDIM + col0;
#pragma unroll
        for (int j = 0; j < 2; ++j)
          Prow[j * 16] = f32_to_bf16(acc[i][j][r]);
      }
  }

  // ================= Phase C: last split-K arrival does RK4 ==============
  __syncthreads();   // drains partial stores; LDS free for the flag
  int* fl = (int*)ldsbuf;
  if (tid == 0) {
    int old = __hip_atomic_fetch_add(&cnt[64 + bm2 * 8 + bn2], 1,
                                     __ATOMIC_ACQ_REL, __HIP_MEMORY_SCOPE_AGENT);
    fl[0] = old;
  }
  __syncthreads();
  if (fl[0] != 3) return;            // not last: done
  (void)__hip_atomic_load(&cnt[64 + bm2 * 8 + bn2], __ATOMIC_ACQUIRE,
                          __HIP_MEMORY_SCOPE_AGENT);

  // k = p0+p1+p2+p3 + b2; RK4 state update for this 64x64 tile.
  int r0 = tid >> 4, c4 = (tid & 15) * 4;
  int colg = bn2 * 64 + c4;
  float4 bb = *(const float4*)(b2 + colg);
  float hh = 0.5f * dt;
  float sx = dt * (1.0f / 6.0f);
#pragma unroll
  for (int i = 0; i < 4; ++i) {
    int rowg = bm2 * 64 + i * 16 + r0;
    size_t off = (size_t)rowg * DDIM + colg;
    ushort4 a = *(const ushort4*)(part + off);
    ushort4 b = *(const ushort4*)(part + (size_t)MDIM * DDIM + off);
    ushort4 c = *(const ushort4*)(part + 2 * (size_t)MDIM * DDIM + off);
    ushort4 d = *(const ushort4*)(part + 3 * (size_t)MDIM * DDIM + off);
    float4 k;
    k.x = bf16_to_f32(a.x) + bf16_to_f32(b.x) + bf16_to_f32(c.x) + bf16_to_f32(d.x) + bb.x;
    k.y = bf16_to_f32(a.y) + bf16_to_f32(b.y) + bf16_to_f32(c.y) + bf16_to_f32(d.y) + bb.y;
    k.z = bf16_to_f32(a.z) + bf16_to_f32(b.z) + bf16_to_f32(c.z) + bf16_to_f32(d.z) + bb.z;
    k.w = bf16_to_f32(a.w) + bf16_to_f32(b.w) + bf16_to_f32(c.w) + bf16_to_f32(d.w) + bb.w;
    float4 yv = *(const float4*)(y + off);
    float4 argv;
    if (mode == 0) {
      *(float4*)(kacc + off) = k;
      argv.x = yv.x + hh * k.x; argv.y = yv.y + hh * k.y;
      argv.z = yv.z + hh * k.z; argv.w = yv.w + hh * k.w;
    } else if (mode == 1) {
      float4 ka = *(const float4*)(kacc + off);
      ka.x += 2.0f * k.x; ka.y += 2.0f * k.y; ka.z += 2.0f * k.z; ka.w += 2.0f * k.w;
      *(float4*)(kacc + off) = ka;
      argv.x = yv.x + hh * k.x; argv.y = yv.y + hh * k.y;
      argv.z = yv.z + hh * k.z; argv.w = yv.w + hh * k.w;
    } else if (mode == 2) {
      float4 ka = *(const float4*)(kacc + off);
      ka.x += 2.0f * k.x; ka.y += 2.0f * k.y; ka.z += 2.0f * k.z; ka.w += 2.0f * k.w;
      *(float4*)(kacc + off) = ka;
      argv.x = yv.x + dt * k.x; argv.y = yv.y + dt * k.y;
      argv.z = yv.z + dt * k.z; argv.w = yv.w + dt * k.w;
    } else {
      float4 ka = *(const float4*)(kacc + off);
      argv.x = yv.x + sx * (ka.x + k.x); argv.y = yv.y + sx * (ka.y + k.y);
      argv.z = yv.z + sx * (ka.z + k.z); argv.w = yv.w + sx * (ka.w + k.w);
      *(float4*)(y + off) = argv;
    }
    ushort4 av;
    av.x = f32_to_bf16(argv.x); av.y = f32_to_bf16(argv.y);
    av.z = f32_to_bf16(argv.z); av.w = f32_to_bf16(argv.w);
    *(ushort4*)(arg + off) = av;     // safe in-place: all readers of these
                                     // rows happened-before via counter chain
  }
}

extern "C" void kernel_launch(void* const* d_in, const int* in_sizes, int n_in,
                              void* d_out, int out_size, void* d_ws, size_t ws_size,
                              hipStream_t stream) {
  (void)in_sizes; (void)n_in; (void)out_size; (void)ws_size;
  const float* x  = (const float*)d_in[0];   // [1024,512]
  const float* W1 = (const float*)d_in[1];   // [512,2048]
  const float* b1 = (const float*)d_in[2];   // [2048]
  const float* W2 = (const float*)d_in[3];   // [2048,512]
  const float* b2 = (const float*)d_in[4];   // [512]
  float* y = (float*)d_out;                  // fp32 state lives in d_out

  char* ws = (char*)d_ws;
  unsigned short* W1T  = (unsigned short*)(ws);                    // 2MB  [2048,512] bf16
  unsigned short* W2T  = (unsigned short*)(ws + (2u << 20));       // 2MB  [512,2048] bf16
  unsigned short* Hbuf = (unsigned short*)(ws + (4u << 20));       // 4MB  [1024,2048] bf16
  unsigned short* arg  = (unsigned short*)(ws + (8u << 20));       // 1MB  [1024,512] bf16
  float*          kacc = (float*)(ws + (9u << 20));                // 2MB  [1024,512] f32
  unsigned short* part = (unsigned short*)(ws + (11u << 20));      // 4MB  [4][1024,512] bf16
  int*            cnts = (int*)(ws + (15u << 20));                 // 48KB [64][192] int

  hipFuncSetAttribute((const void*)fused_eval_kernel,
                      hipFuncAttributeMaxDynamicSharedMemorySize, GEMM_LDS);

  transpose_bf16_kernel<<<256, 256, 0, stream>>>(W1, W1T, DDIM, HDIM);
  transpose_bf16_kernel<<<256, 256, 0, stream>>>(W2, W2T, HDIM, DDIM);
  init_kernel<<<MDIM * DDIM / 256, 256, 0, stream>>>(x, y, arg, cnts);

  const float dt = 1.0f / 16.0f;
  for (int n = 0; n < 16; ++n) {
    float t0 = dt * (float)n;
    const float ts[4] = {t0, t0 + 0.5f * dt, t0 + 0.5f * dt, t0 + dt};
    for (int s = 0; s < 4; ++s) {
      int e = n * 4 + s;
      fused_eval_kernel<<<512, 256, GEMM_LDS, stream>>>(
          arg, W1T, b1, W2T, Hbuf, part, b2, y, kacc,
          cnts + e * 192, ts[s], s, dt);
    }
  }
}

// Round 5
// 1309.014 us; speedup vs baseline: 3.9099x; 3.9099x over previous
//
#include <hip/hip_runtime.h>
#include <cstdint>

// ODEBlock: 16 RK4 steps of f(t,y) = tanh(y@W1 + b1 + t) @ W2 + b2
// B=1024 (M), D=512, H=2048. bf16 MFMA GEMMs, fp32 state/epilogues.
// R18: back to the PROVEN dispatch-boundary structure (R13, 1249us), minus
// the combine kernel: gemm2 now owns FULL-K output tiles and its epilogue
// does the RK4 update directly. No cross-block sync, no coherence games
// (R14: acq/rel wbl2 storm 4x slow; R15/R17: sc0sc1 stores don't write
// through gfx950 L2 -> stale MALL reads -> wrong results. Mega-kernel dead.)
// gemm2rk4: tile 32x64, 512 thr (8 waves), K=2048 split across 2 in-block
// wave-groups (each 4 waves, 2x2 over 32x64, 8 kt of BK=128), LDS dbuf
// 48KB/group (96KB total, 1 blk/CU), fp32 LDS reduction (8KB overlay) +
// float4-linear RK4 epilogue. Grid 256 x 512thr = full machine, 2 w/SIMD.
// Removes: combine dispatch + launch gap + bf16 part round-trip (accuracy up).
// gemm1 unchanged from R13 best (64x64, BK=128, XOR-swizzle, 64KB dbuf).
// Dispatches: 195 -> 131.

typedef __bf16 bf16x8 __attribute__((ext_vector_type(8)));
typedef float f32x4 __attribute__((ext_vector_type(4)));

#define AS1 __attribute__((address_space(1)))
#define AS3 __attribute__((address_space(3)))

#define MDIM 1024
#define DDIM 512
#define HDIM 2048

#define GEMM_LDS (64 * 1024)    // gemm1: sA 2x16KB + sB 2x16KB
#define GEMM2_LDS (96 * 1024)   // gemm2rk4: 2 groups x (sA 2x8KB + sB 2x16KB)

__device__ __forceinline__ void async_copy16(const void* g, void* lds) {
  __builtin_amdgcn_global_load_lds((const AS1 void*)g, (AS3 void*)lds, 16, 0, 0);
}

__device__ __forceinline__ unsigned short f32_to_bf16(float f) {
  union { float f; unsigned u; } c; c.f = f;
  unsigned u = c.u + 0x7FFFu + ((c.u >> 16) & 1u);   // RNE
  return (unsigned short)(u >> 16);
}

__device__ __forceinline__ float tanh_fast(float x) {
  float a = __builtin_fabsf(x);
  float e = __expf(-2.0f * a);                        // in (0,1], no overflow
  float r = (1.0f - e) * __builtin_amdgcn_rcpf(1.0f + e);
  return __builtin_copysignf(r, x);
}

// ---- transpose + f32->bf16: out[c*R + r] = bf16(in[r*C + c]) --------------
__global__ __launch_bounds__(256) void transpose_bf16_kernel(
    const float* __restrict__ in, unsigned short* __restrict__ out, int R, int C) {
  __shared__ float tile[64][65];
  int nbc = C >> 6;
  int br = blockIdx.x / nbc, bc = blockIdx.x % nbc;
  int r0 = br * 64, c0 = bc * 64;
  int tr = threadIdx.x >> 6, tc = threadIdx.x & 63;
  for (int i = 0; i < 16; ++i) {
    int row = i * 4 + tr;
    tile[row][tc] = in[(r0 + row) * C + c0 + tc];
  }
  __syncthreads();
  for (int i = 0; i < 16; ++i) {
    int row = i * 4 + tr;
    out[(c0 + row) * R + r0 + tc] = f32_to_bf16(tile[tc][row]);
  }
}

// ---- init: y = x (fp32, lives in d_out), arg = bf16(x) --------------------
__global__ __launch_bounds__(256) void init_kernel(
    const float* __restrict__ x, float* __restrict__ y,
    unsigned short* __restrict__ arg) {
  int i = blockIdx.x * 256 + threadIdx.x;
  float v = x[i];
  y[i] = v;
  arg[i] = f32_to_bf16(v);
}

// ---- GEMM1: H = tanh(arg[1024,512] @ W1 + b1 + t) -------------------------
// Unchanged from R13 (proven 1249us config). Tile 64x64, BK=128, grid 512
// (2 blocks/CU), 4 waves 2x2, wave 32x32, LDS dbuf 64KB, XOR-swizzled.
__global__ __launch_bounds__(256, 2) void gemm1_kernel(
    const unsigned short* __restrict__ A,    // arg bf16 [1024,512]
    const unsigned short* __restrict__ Bt,   // W1T bf16 [2048,512]
    const float* __restrict__ b1, float tval,
    unsigned short* __restrict__ H)          // [1024,2048] bf16
{
  extern __shared__ char ldsbuf[];
  bf16x8* sA = (bf16x8*)ldsbuf;              // 2 x 1024 units (32KB)
  bf16x8* sB = (bf16x8*)(ldsbuf + 32768);    // 2 x 1024 units (32KB)
  const int K = DDIM;
  const int NITER = 4;            // 512 / 128
  int bid = blockIdx.x;
  int bm = bid >> 5;              // 0..15
  int bn = bid & 31;              // 0..31
  int tid = threadIdx.x;
  int lane = tid & 63;
  int wid = tid >> 6;
  int l15 = lane & 15;
  int l4 = lane >> 4;
  int wm = (wid >> 1) * 32;
  int wn = (wid & 1) * 32;
  int sw = l15 & 7;               // read-side swizzle (row & 7)

  const unsigned short* gA[4];
  const unsigned short* gB[4];
#pragma unroll
  for (int i = 0; i < 4; ++i) {
    int u = tid + i * 256, r = u >> 4, s = u & 15;
    int koff = ((s ^ (r & 7)) * 8);
    gA[i] = A + (size_t)(bm * 64 + r) * K + koff;
    gB[i] = Bt + (size_t)(bn * 64 + r) * K + koff;
  }
  f32x4 acc[2][2] = {};

#pragma unroll
  for (int i = 0; i < 4; ++i) {
    async_copy16(gA[i], &sA[tid + i * 256]);
    async_copy16(gB[i], &sB[tid + i * 256]);
  }

#pragma unroll 1
  for (int kt = 0; kt < NITER; ++kt) {
    int cur = kt & 1;
    __syncthreads();
    if (kt + 1 < NITER) {
      int nxt = cur ^ 1;
      int off = (kt + 1) * 128;
#pragma unroll
      for (int i = 0; i < 4; ++i) {
        async_copy16(gA[i] + off, &sA[nxt * 1024 + tid + i * 256]);
        async_copy16(gB[i] + off, &sB[nxt * 1024 + tid + i * 256]);
      }
    }
#pragma unroll
    for (int ks = 0; ks < 4; ++ks) {
      int kg = (ks * 4 + l4) ^ sw;
      bf16x8 af[2], bfr[2];
#pragma unroll
      for (int i = 0; i < 2; ++i)
        af[i] = sA[cur * 1024 + (wm + i * 16 + l15) * 16 + kg];
#pragma unroll
      for (int j = 0; j < 2; ++j)
        bfr[j] = sB[cur * 1024 + (wn + j * 16 + l15) * 16 + kg];
#pragma unroll
      for (int i = 0; i < 2; ++i)
#pragma unroll
        for (int j = 0; j < 2; ++j)
          acc[i][j] = __builtin_amdgcn_mfma_f32_16x16x32_bf16(
              af[i], bfr[j], acc[i][j], 0, 0, 0);
    }
  }
  int row0 = bm * 64 + wm + l4 * 4;
  int col0 = bn * 64 + wn + l15;
  float bias[2];
  for (int j = 0; j < 2; ++j) bias[j] = b1[col0 + j * 16] + tval;
#pragma unroll
  for (int i = 0; i < 2; ++i)
#pragma unroll
    for (int r = 0; r < 4; ++r) {
      unsigned short* Hrow = H + (size_t)(row0 + i * 16 + r) * HDIM + col0;
#pragma unroll
      for (int j = 0; j < 2; ++j)
        Hrow[j * 16] = f32_to_bf16(tanh_fast(acc[i][j][r] + bias[j]));
    }
}

// ---- GEMM2 + RK4: k = H @ W2T' + b2, then RK4 state update ----------------
// Tile 32x64 (M x N), FULL K=2048. 512 threads = 8 waves = 2 K-groups of 4.
// Group g: K in [g*1024, g*1024+1024), 8 kt of BK=128, waves 2x2 over
// (32,64) -> wave 16x32, acc f32x4[2] (1x2 frags). Then LDS fp32 reduce
// (8KB overlay on dead staging) + linear float4 RK4 epilogue.
// mode 0: kacc = k;            arg = bf16(y + dt/2*k)
// mode 1: kacc += 2k;          arg = bf16(y + dt/2*k)
// mode 2: kacc += 2k;          arg = bf16(y + dt*k)
// mode 3: y += dt/6*(kacc+k);  arg = bf16(y_new)
__global__ __launch_bounds__(512, 1) void gemm2rk4_kernel(
    const unsigned short* __restrict__ A,    // H bf16 [1024,2048]
    const unsigned short* __restrict__ Bt,   // W2T bf16 [512,2048]
    const float* __restrict__ b2,
    float* __restrict__ y, float* __restrict__ kacc,
    unsigned short* __restrict__ arg, int mode, float dt)
{
  extern __shared__ char ldsbuf[];
  // per-group layout (units of 16B): gbase = wg*3072
  //   sA dbuf: [2][512]  (32 rows x 16 slots)   16KB
  //   sB dbuf: [2][1024] (64 rows x 16 slots)   32KB
  bf16x8* su = (bf16x8*)ldsbuf;
  const int K = HDIM;
  int bid = blockIdx.x;
  int bm = bid >> 3;              // 0..31  (rows bm*32..)
  int bn = bid & 7;               // 0..7   (cols bn*64..)
  int tid = threadIdx.x;
  int tl = tid & 255;             // group-local thread
  int wg = tid >> 8;              // K-group 0/1
  int lane = tid & 63;
  int wid = tid >> 6;
  int wq = wid & 3;               // quadrant within group
  int l15 = lane & 15;
  int l4 = lane >> 4;
  int wm = (wq >> 1) * 16;        // 0 / 16
  int wn = (wq & 1) * 32;         // 0 / 32
  int sw = l15 & 7;
  int gbase = wg * 3072;
  int k0 = wg * 1024;

  // staging pointers (XOR-swizzled k-slots)
  const unsigned short* gA[2];    // A units: 512 (2/thread)
  const unsigned short* gB[4];    // B units: 1024 (4/thread)
#pragma unroll
  for (int i = 0; i < 2; ++i) {
    int u = tl + i * 256, r = u >> 4, sl = u & 15;
    gA[i] = A + (size_t)(bm * 32 + r) * K + k0 + ((sl ^ (r & 7)) * 8);
  }
#pragma unroll
  for (int i = 0; i < 4; ++i) {
    int u = tl + i * 256, r = u >> 4, sl = u & 15;
    gB[i] = Bt + (size_t)(bn * 64 + r) * K + k0 + ((sl ^ (r & 7)) * 8);
  }
  f32x4 acc[2] = {};

#pragma unroll
  for (int i = 0; i < 2; ++i)
    async_copy16(gA[i], &su[gbase + tl + i * 256]);
#pragma unroll
  for (int i = 0; i < 4; ++i)
    async_copy16(gB[i], &su[gbase + 1024 + tl + i * 256]);

#pragma unroll 1
  for (int kt = 0; kt < 8; ++kt) {
    int cur = kt & 1;
    __syncthreads();
    if (kt + 1 < 8) {
      int nxt = cur ^ 1;
      int off = (kt + 1) * 128;
#pragma unroll
      for (int i = 0; i < 2; ++i)
        async_copy16(gA[i] + off, &su[gbase + nxt * 512 + tl + i * 256]);
#pragma unroll
      for (int i = 0; i < 4; ++i)
        async_copy16(gB[i] + off, &su[gbase + 1024 + nxt * 1024 + tl + i * 256]);
    }
#pragma unroll
    for (int ks = 0; ks < 4; ++ks) {
      int kg = (ks * 4 + l4) ^ sw;
      bf16x8 af = su[gbase + cur * 512 + (wm + l15) * 16 + kg];
      bf16x8 bfr[2];
#pragma unroll
      for (int j = 0; j < 2; ++j)
        bfr[j] = su[gbase + 1024 + cur * 1024 + (wn + j * 16 + l15) * 16 + kg];
#pragma unroll
      for (int j = 0; j < 2; ++j)
        acc[j] = __builtin_amdgcn_mfma_f32_16x16x32_bf16(af, bfr[j], acc[j], 0, 0, 0);
    }
  }

  // ---- fp32 reduction across the 2 K-groups (overlay on dead staging) ----
  float* red = (float*)ldsbuf;             // [32][64] f32 = 8KB
  int orow = wm + l4 * 4;                  // + r
  int ocol = wn + l15;                     // + j*16
  __syncthreads();                         // staging reads done, safe to overlay
  if (wg == 0) {
#pragma unroll
    for (int j = 0; j < 2; ++j)
#pragma unroll
      for (int r = 0; r < 4; ++r)
        red[(orow + r) * 64 + ocol + j * 16] = acc[j][r];
  }
  __syncthreads();
  if (wg == 1) {
#pragma unroll
    for (int j = 0; j < 2; ++j)
#pragma unroll
      for (int r = 0; r < 4; ++r)
        red[(orow + r) * 64 + ocol + j * 16] += acc[j][r];
  }
  __syncthreads();

  // ---- RK4 epilogue, linear float4 mapping: 512 thr x 4 elems ----
  int row = tid >> 4;                      // 0..31
  int c0 = (tid & 15) * 4;                 // 0..60
  int grow = bm * 32 + row;
  int gcol = bn * 64 + c0;
  size_t off = (size_t)grow * DDIM + gcol;
  float4 bb = *(const float4*)(b2 + gcol);
  float4 k;
  k.x = red[row * 64 + c0 + 0] + bb.x;
  k.y = red[row * 64 + c0 + 1] + bb.y;
  k.z = red[row * 64 + c0 + 2] + bb.z;
  k.w = red[row * 64 + c0 + 3] + bb.w;
  float4 yv = *(const float4*)(y + off);
  float hh = 0.5f * dt;
  float sx = dt * (1.0f / 6.0f);
  float4 argv;
  if (mode == 0) {
    *(float4*)(kacc + off) = k;
    argv.x = yv.x + hh * k.x; argv.y = yv.y + hh * k.y;
    argv.z = yv.z + hh * k.z; argv.w = yv.w + hh * k.w;
  } else if (mode == 1) {
    float4 ka = *(const float4*)(kacc + off);
    ka.x += 2.0f * k.x; ka.y += 2.0f * k.y; ka.z += 2.0f * k.z; ka.w += 2.0f * k.w;
    *(float4*)(kacc + off) = ka;
    argv.x = yv.x + hh * k.x; argv.y = yv.y + hh * k.y;
    argv.z = yv.z + hh * k.z; argv.w = yv.w + hh * k.w;
  } else if (mode == 2) {
    float4 ka = *(const float4*)(kacc + off);
    ka.x += 2.0f * k.x; ka.y += 2.0f * k.y; ka.z += 2.0f * k.z; ka.w += 2.0f * k.w;
    *(float4*)(kacc + off) = ka;
    argv.x = yv.x + dt * k.x; argv.y = yv.y + dt * k.y;
    argv.z = yv.z + dt * k.z; argv.w = yv.w + dt * k.w;
  } else {
    float4 ka = *(const float4*)(kacc + off);
    argv.x = yv.x + sx * (ka.x + k.x); argv.y = yv.y + sx * (ka.y + k.y);
    argv.z = yv.z + sx * (ka.z + k.z); argv.w = yv.w + sx * (ka.w + k.w);
    *(float4*)(y + off) = argv;
  }
  ushort4 av;
  av.x = f32_to_bf16(argv.x); av.y = f32_to_bf16(argv.y);
  av.z = f32_to_bf16(argv.z); av.w = f32_to_bf16(argv.w);
  *(ushort4*)(arg + off) = av;
}

extern "C" void kernel_launch(void* const* d_in, const int* in_sizes, int n_in,
                              void* d_out, int out_size, void* d_ws, size_t ws_size,
                              hipStream_t stream) {
  (void)in_sizes; (void)n_in; (void)out_size; (void)ws_size;
  const float* x  = (const float*)d_in[0];   // [1024,512]
  const float* W1 = (const float*)d_in[1];   // [512,2048]
  const float* b1 = (const float*)d_in[2];   // [2048]
  const float* W2 = (const float*)d_in[3];   // [2048,512]
  const float* b2 = (const float*)d_in[4];   // [512]
  float* y = (float*)d_out;                  // fp32 state lives in d_out

  char* ws = (char*)d_ws;
  unsigned short* W1T  = (unsigned short*)(ws);                    // 2MB  [2048,512] bf16
  unsigned short* W2T  = (unsigned short*)(ws + (2u << 20));       // 2MB  [512,2048] bf16
  unsigned short* Hbuf = (unsigned short*)(ws + (4u << 20));       // 4MB  [1024,2048] bf16
  unsigned short* arg  = (unsigned short*)(ws + (8u << 20));       // 1MB  [1024,512] bf16
  float*          kacc = (float*)(ws + (9u << 20));                // 2MB  [1024,512] f32

  hipFuncSetAttribute((const void*)gemm1_kernel,
                      hipFuncAttributeMaxDynamicSharedMemorySize, GEMM_LDS);
  hipFuncSetAttribute((const void*)gemm2rk4_kernel,
                      hipFuncAttributeMaxDynamicSharedMemorySize, GEMM2_LDS);

  transpose_bf16_kernel<<<256, 256, 0, stream>>>(W1, W1T, DDIM, HDIM);
  transpose_bf16_kernel<<<256, 256, 0, stream>>>(W2, W2T, HDIM, DDIM);
  init_kernel<<<MDIM * DDIM / 256, 256, 0, stream>>>(x, y, arg);

  const float dt = 1.0f / 16.0f;
  for (int n = 0; n < 16; ++n) {
    float t0 = dt * (float)n;
    const float ts[4] = {t0, t0 + 0.5f * dt, t0 + 0.5f * dt, t0 + dt};
    for (int s = 0; s < 4; ++s) {
      gemm1_kernel<<<512, 256, GEMM_LDS, stream>>>(arg, W1T, b1, ts[s], Hbuf);
      gemm2rk4_kernel<<<256, 512, GEMM2_LDS, stream>>>(Hbuf, W2T, b2, y, kacc, arg, s, dt);
    }
  }
}

// Round 7
// 1145.501 us; speedup vs baseline: 4.4681x; 1.1427x over previous
//
#include <hip/hip_runtime.h>
#include <cstdint>

// ODEBlock: 16 RK4 steps of f(t,y) = tanh(y@W1 + b1 + t) @ W2 + b2
// B=1024 (M), D=512, H=2048. bf16 MFMA GEMMs, fp32 state/epilogues.
// R19 (resubmit; previous round was an infra failure, no signal):
// 2 dispatches per eval (gemm1, gemm2rk4), with gemm2rk4 rebuilt to
// R13's proven geometry. R18's regression (+60us) was geometry, not fusion:
// 1 block/CU (96KB LDS, 512thr) + thin 16x32 wave tiles. R19 gemm2rk4:
//   - 32x32 output tiles, FULL K=2048 -> grid 32x16=512 blocks
//   - 256 thr / 4 waves; wave w owns K-window [w*512, w*512+512)
//     over the whole 32x32 tile -> wave tile 2x2 frags (4 MFMA : 4 reads,
//     same ratio as R13's proven gemm2)
//   - BK=64 dbuf: 2 x (4 windows x 32rows x 64k) x (A,B) = 64KB LDS
//     -> 2 blocks/CU (same as R13)
//   - fp32 cross-wave reduction in 18KB LDS overlay + RK4 epilogue
// Removes per eval: combine dispatch + launch gap + bf16 part round-trip.
// Coherence: dispatch-boundary only (proven R13/R18); no sync tricks
// (R14 wbl2 storm 4x; R15/R17 stale-L2 wrong results -> line abandoned).
// gemm1 unchanged from R13 best. Dispatches: 195 -> 131.

typedef __bf16 bf16x8 __attribute__((ext_vector_type(8)));
typedef float f32x4 __attribute__((ext_vector_type(4)));

#define AS1 __attribute__((address_space(1)))
#define AS3 __attribute__((address_space(3)))

#define MDIM 1024
#define DDIM 512
#define HDIM 2048

#define GEMM_LDS (64 * 1024)    // gemm1: sA 2x16KB + sB 2x16KB
#define GEMM2_LDS (64 * 1024)   // gemm2rk4: sA 2x16KB + sB 2x16KB (BK=64 x 4 win)

__device__ __forceinline__ void async_copy16(const void* g, void* lds) {
  __builtin_amdgcn_global_load_lds((const AS1 void*)g, (AS3 void*)lds, 16, 0, 0);
}

__device__ __forceinline__ unsigned short f32_to_bf16(float f) {
  union { float f; unsigned u; } c; c.f = f;
  unsigned u = c.u + 0x7FFFu + ((c.u >> 16) & 1u);   // RNE
  return (unsigned short)(u >> 16);
}

__device__ __forceinline__ float tanh_fast(float x) {
  float a = __builtin_fabsf(x);
  float e = __expf(-2.0f * a);                        // in (0,1], no overflow
  float r = (1.0f - e) * __builtin_amdgcn_rcpf(1.0f + e);
  return __builtin_copysignf(r, x);
}

// ---- transpose + f32->bf16: out[c*R + r] = bf16(in[r*C + c]) --------------
__global__ __launch_bounds__(256) void transpose_bf16_kernel(
    const float* __restrict__ in, unsigned short* __restrict__ out, int R, int C) {
  __shared__ float tile[64][65];
  int nbc = C >> 6;
  int br = blockIdx.x / nbc, bc = blockIdx.x % nbc;
  int r0 = br * 64, c0 = bc * 64;
  int tr = threadIdx.x >> 6, tc = threadIdx.x & 63;
  for (int i = 0; i < 16; ++i) {
    int row = i * 4 + tr;
    tile[row][tc] = in[(r0 + row) * C + c0 + tc];
  }
  __syncthreads();
  for (int i = 0; i < 16; ++i) {
    int row = i * 4 + tr;
    out[(c0 + row) * R + r0 + tc] = f32_to_bf16(tile[tc][row]);
  }
}

// ---- init: y = x (fp32, lives in d_out), arg = bf16(x) --------------------
__global__ __launch_bounds__(256) void init_kernel(
    const float* __restrict__ x, float* __restrict__ y,
    unsigned short* __restrict__ arg) {
  int i = blockIdx.x * 256 + threadIdx.x;
  float v = x[i];
  y[i] = v;
  arg[i] = f32_to_bf16(v);
}

// ---- GEMM1: H = tanh(arg[1024,512] @ W1 + b1 + t) -------------------------
// Unchanged from R13 (proven 1249us config). Tile 64x64, BK=128, grid 512
// (2 blocks/CU), 4 waves 2x2, wave 32x32, LDS dbuf 64KB, XOR-swizzled.
__global__ __launch_bounds__(256, 2) void gemm1_kernel(
    const unsigned short* __restrict__ A,    // arg bf16 [1024,512]
    const unsigned short* __restrict__ Bt,   // W1T bf16 [2048,512]
    const float* __restrict__ b1, float tval,
    unsigned short* __restrict__ H)          // [1024,2048] bf16
{
  extern __shared__ char ldsbuf[];
  bf16x8* sA = (bf16x8*)ldsbuf;              // 2 x 1024 units (32KB)
  bf16x8* sB = (bf16x8*)(ldsbuf + 32768);    // 2 x 1024 units (32KB)
  const int K = DDIM;
  const int NITER = 4;            // 512 / 128
  int bid = blockIdx.x;
  int bm = bid >> 5;              // 0..15
  int bn = bid & 31;              // 0..31
  int tid = threadIdx.x;
  int lane = tid & 63;
  int wid = tid >> 6;
  int l15 = lane & 15;
  int l4 = lane >> 4;
  int wm = (wid >> 1) * 32;
  int wn = (wid & 1) * 32;
  int sw = l15 & 7;               // read-side swizzle (row & 7)

  const unsigned short* gA[4];
  const unsigned short* gB[4];
#pragma unroll
  for (int i = 0; i < 4; ++i) {
    int u = tid + i * 256, r = u >> 4, s = u & 15;
    int koff = ((s ^ (r & 7)) * 8);
    gA[i] = A + (size_t)(bm * 64 + r) * K + koff;
    gB[i] = Bt + (size_t)(bn * 64 + r) * K + koff;
  }
  f32x4 acc[2][2] = {};

#pragma unroll
  for (int i = 0; i < 4; ++i) {
    async_copy16(gA[i], &sA[tid + i * 256]);
    async_copy16(gB[i], &sB[tid + i * 256]);
  }

#pragma unroll 1
  for (int kt = 0; kt < NITER; ++kt) {
    int cur = kt & 1;
    __syncthreads();
    if (kt + 1 < NITER) {
      int nxt = cur ^ 1;
      int off = (kt + 1) * 128;
#pragma unroll
      for (int i = 0; i < 4; ++i) {
        async_copy16(gA[i] + off, &sA[nxt * 1024 + tid + i * 256]);
        async_copy16(gB[i] + off, &sB[nxt * 1024 + tid + i * 256]);
      }
    }
#pragma unroll
    for (int ks = 0; ks < 4; ++ks) {
      int kg = (ks * 4 + l4) ^ sw;
      bf16x8 af[2], bfr[2];
#pragma unroll
      for (int i = 0; i < 2; ++i)
        af[i] = sA[cur * 1024 + (wm + i * 16 + l15) * 16 + kg];
#pragma unroll
      for (int j = 0; j < 2; ++j)
        bfr[j] = sB[cur * 1024 + (wn + j * 16 + l15) * 16 + kg];
#pragma unroll
      for (int i = 0; i < 2; ++i)
#pragma unroll
        for (int j = 0; j < 2; ++j)
          acc[i][j] = __builtin_amdgcn_mfma_f32_16x16x32_bf16(
              af[i], bfr[j], acc[i][j], 0, 0, 0);
    }
  }
  int row0 = bm * 64 + wm + l4 * 4;
  int col0 = bn * 64 + wn + l15;
  float bias[2];
  for (int j = 0; j < 2; ++j) bias[j] = b1[col0 + j * 16] + tval;
#pragma unroll
  for (int i = 0; i < 2; ++i)
#pragma unroll
    for (int r = 0; r < 4; ++r) {
      unsigned short* Hrow = H + (size_t)(row0 + i * 16 + r) * HDIM + col0;
#pragma unroll
      for (int j = 0; j < 2; ++j)
        Hrow[j * 16] = f32_to_bf16(tanh_fast(acc[i][j][r] + bias[j]));
    }
}

// ---- GEMM2 + RK4: k = H @ W2T' + b2, then RK4 state update ----------------
// Tile 32x32 (M x N), FULL K=2048. Grid 32x16 = 512 blocks, 256 thr.
// Wave w (0..3) computes the whole 32x32 tile over K-window [w*512,+512):
// 8 kt of BK=64, acc 2x2 frags. LDS: unit u (16B) -> (win=u>>8, r=(u>>3)&31,
// slot=u&7), XOR swizzle slot^(r&7). Then fp32 reduce over 4 windows in an
// 18KB LDS overlay (pitch 36 floats: conflict-free) + RK4 epilogue.
// mode 0: kacc = k;            arg = bf16(y + dt/2*k)
// mode 1: kacc += 2k;          arg = bf16(y + dt/2*k)
// mode 2: kacc += 2k;          arg = bf16(y + dt*k)
// mode 3: y += dt/6*(kacc+k);  arg = bf16(y_new)
__global__ __launch_bounds__(256, 2) void gemm2rk4_kernel(
    const unsigned short* __restrict__ A,    // H bf16 [1024,2048]
    const unsigned short* __restrict__ Bt,   // W2T bf16 [512,2048]
    const float* __restrict__ b2,
    float* __restrict__ y, float* __restrict__ kacc,
    unsigned short* __restrict__ arg, int mode, float dt)
{
  extern __shared__ char ldsbuf[];
  bf16x8* sA = (bf16x8*)ldsbuf;              // 2 x 1024 units (32KB)
  bf16x8* sB = (bf16x8*)(ldsbuf + 32768);    // 2 x 1024 units (32KB)
  const int K = HDIM;
  int bid = blockIdx.x;
  int bm = bid >> 4;              // 0..31 (rows bm*32..)
  int bn = bid & 15;              // 0..15 (cols bn*32..)
  int tid = threadIdx.x;
  int lane = tid & 63;
  int wid = tid >> 6;             // wave = K-window 0..3
  int l15 = lane & 15;
  int l4 = lane >> 4;
  int sw = l15 & 7;

  // staging: 1024 units each (4/thread); u -> (win, row, slot)
  const unsigned short* gA[4];
  const unsigned short* gB[4];
#pragma unroll
  for (int i = 0; i < 4; ++i) {
    int u = tid + i * 256;
    int w = u >> 8, r = (u >> 3) & 31, sl = u & 7;
    int koff = w * 512 + ((sl ^ (r & 7)) * 8);
    gA[i] = A  + (size_t)(bm * 32 + r) * K + koff;
    gB[i] = Bt + (size_t)(bn * 32 + r) * K + koff;
  }
  f32x4 acc[2][2] = {};

#pragma unroll
  for (int i = 0; i < 4; ++i) {
    async_copy16(gA[i], &sA[tid + i * 256]);
    async_copy16(gB[i], &sB[tid + i * 256]);
  }

#pragma unroll 1
  for (int kt = 0; kt < 8; ++kt) {
    int cur = kt & 1;
    __syncthreads();
    if (kt + 1 < 8) {
      int nxt = cur ^ 1;
      int off = (kt + 1) * 64;
#pragma unroll
      for (int i = 0; i < 4; ++i) {
        async_copy16(gA[i] + off, &sA[nxt * 1024 + tid + i * 256]);
        async_copy16(gB[i] + off, &sB[nxt * 1024 + tid + i * 256]);
      }
    }
#pragma unroll
    for (int ks = 0; ks < 2; ++ks) {
      int kg = (ks * 4 + l4) ^ sw;
      bf16x8 af[2], bfr[2];
#pragma unroll
      for (int i = 0; i < 2; ++i)
        af[i] = sA[cur * 1024 + wid * 256 + (i * 16 + l15) * 8 + kg];
#pragma unroll
      for (int j = 0; j < 2; ++j)
        bfr[j] = sB[cur * 1024 + wid * 256 + (j * 16 + l15) * 8 + kg];
#pragma unroll
      for (int i = 0; i < 2; ++i)
#pragma unroll
        for (int j = 0; j < 2; ++j)
          acc[i][j] = __builtin_amdgcn_mfma_f32_16x16x32_bf16(
              af[i], bfr[j], acc[i][j], 0, 0, 0);
    }
  }

  // ---- fp32 reduction over the 4 K-windows (overlay on dead staging) ----
  __syncthreads();                         // all staging reads complete
  float* red = (float*)ldsbuf;             // [4][32][36] f32 = 18KB
#pragma unroll
  for (int i = 0; i < 2; ++i)
#pragma unroll
    for (int j = 0; j < 2; ++j)
#pragma unroll
      for (int q = 0; q < 4; ++q) {
        int row = i * 16 + l4 * 4 + q;
        int col = j * 16 + l15;
        red[(wid * 32 + row) * 36 + col] = acc[i][j][q];
      }
  __syncthreads();

  // ---- RK4 epilogue: 256 thr x 4 elems over the 32x32 tile ----
  int row = tid >> 3;                      // 0..31
  int c4 = (tid & 7) * 4;                  // 0..28
  float4 s0 = *(float4*)&red[(0 * 32 + row) * 36 + c4];
  float4 s1 = *(float4*)&red[(1 * 32 + row) * 36 + c4];
  float4 s2 = *(float4*)&red[(2 * 32 + row) * 36 + c4];
  float4 s3 = *(float4*)&red[(3 * 32 + row) * 36 + c4];
  int grow = bm * 32 + row;
  int gcol = bn * 32 + c4;
  size_t off = (size_t)grow * DDIM + gcol;
  float4 bb = *(const float4*)(b2 + gcol);
  float4 k;
  k.x = s0.x + s1.x + s2.x + s3.x + bb.x;
  k.y = s0.y + s1.y + s2.y + s3.y + bb.y;
  k.z = s0.z + s1.z + s2.z + s3.z + bb.z;
  k.w = s0.w + s1.w + s2.w + s3.w + bb.w;
  float4 yv = *(const float4*)(y + off);
  float hh = 0.5f * dt;
  float sx = dt * (1.0f / 6.0f);
  float4 argv;
  if (mode == 0) {
    *(float4*)(kacc + off) = k;
    argv.x = yv.x + hh * k.x; argv.y = yv.y + hh * k.y;
    argv.z = yv.z + hh * k.z; argv.w = yv.w + hh * k.w;
  } else if (mode == 1) {
    float4 ka = *(const float4*)(kacc + off);
    ka.x += 2.0f * k.x; ka.y += 2.0f * k.y; ka.z += 2.0f * k.z; ka.w += 2.0f * k.w;
    *(float4*)(kacc + off) = ka;
    argv.x = yv.x + hh * k.x; argv.y = yv.y + hh * k.y;
    argv.z = yv.z + hh * k.z; argv.w = yv.w + hh * k.w;
  } else if (mode == 2) {
    float4 ka = *(const float4*)(kacc + off);
    ka.x += 2.0f * k.x; ka.y += 2.0f * k.y; ka.z += 2.0f * k.z; ka.w += 2.0f * k.w;
    *(float4*)(kacc + off) = ka;
    argv.x = yv.x + dt * k.x; argv.y = yv.y + dt * k.y;
    argv.z = yv.z + dt * k.z; argv.w = yv.w + dt * k.w;
  } else {
    float4 ka = *(const float4*)(kacc + off);
    argv.x = yv.x + sx * (ka.x + k.x); argv.y = yv.y + sx * (ka.y + k.y);
    argv.z = yv.z + sx * (ka.z + k.z); argv.w = yv.w + sx * (ka.w + k.w);
    *(float4*)(y + off) = argv;
  }
  ushort4 av;
  av.x = f32_to_bf16(argv.x); av.y = f32_to_bf16(argv.y);
  av.z = f32_to_bf16(argv.z); av.w = f32_to_bf16(argv.w);
  *(ushort4*)(arg + off) = av;
}

extern "C" void kernel_launch(void* const* d_in, const int* in_sizes, int n_in,
                              void* d_out, int out_size, void* d_ws, size_t ws_size,
                              hipStream_t stream) {
  (void)in_sizes; (void)n_in; (void)out_size; (void)ws_size;
  const float* x  = (const float*)d_in[0];   // [1024,512]
  const float* W1 = (const float*)d_in[1];   // [512,2048]
  const float* b1 = (const float*)d_in[2];   // [2048]
  const float* W2 = (const float*)d_in[3];   // [2048,512]
  const float* b2 = (const float*)d_in[4];   // [512]
  float* y = (float*)d_out;                  // fp32 state lives in d_out

  char* ws = (char*)d_ws;
  unsigned short* W1T  = (unsigned short*)(ws);                    // 2MB  [2048,512] bf16
  unsigned short* W2T  = (unsigned short*)(ws + (2u << 20));       // 2MB  [512,2048] bf16
  unsigned short* Hbuf = (unsigned short*)(ws + (4u << 20));       // 4MB  [1024,2048] bf16
  unsigned short* arg  = (unsigned short*)(ws + (8u << 20));       // 1MB  [1024,512] bf16
  float*          kacc = (float*)(ws + (9u << 20));                // 2MB  [1024,512] f32

  hipFuncSetAttribute((const void*)gemm1_kernel,
                      hipFuncAttributeMaxDynamicSharedMemorySize, GEMM_LDS);
  hipFuncSetAttribute((const void*)gemm2rk4_kernel,
                      hipFuncAttributeMaxDynamicSharedMemorySize, GEMM2_LDS);

  transpose_bf16_kernel<<<256, 256, 0, stream>>>(W1, W1T, DDIM, HDIM);
  transpose_bf16_kernel<<<256, 256, 0, stream>>>(W2, W2T, HDIM, DDIM);
  init_kernel<<<MDIM * DDIM / 256, 256, 0, stream>>>(x, y, arg);

  const float dt = 1.0f / 16.0f;
  for (int n = 0; n < 16; ++n) {
    float t0 = dt * (float)n;
    const float ts[4] = {t0, t0 + 0.5f * dt, t0 + 0.5f * dt, t0 + dt};
    for (int s = 0; s < 4; ++s) {
      gemm1_kernel<<<512, 256, GEMM_LDS, stream>>>(arg, W1T, b1, ts[s], Hbuf);
      gemm2rk4_kernel<<<512, 256, GEMM2_LDS, stream>>>(Hbuf, W2T, b2, y, kacc, arg, s, dt);
    }
  }
}

// Round 8
// 1090.120 us; speedup vs baseline: 4.6951x; 1.0508x over previous
//
#include <hip/hip_runtime.h>
#include <cstdint>

// ODEBlock: 16 RK4 steps of f(t,y) = tanh(y@W1 + b1 + t) @ W2 + b2
// B=1024 (M), D=512, H=2048. bf16 MFMA GEMMs, fp32 state/epilogues.
// R20 = R19 (1145us, best) + XCD-aware block swizzle (T1) in both GEMMs.
// Dispatch round-robins bid%8 -> XCD; lid=(bid&7)*64+(bid>>3) makes each
// XCD own a contiguous lid range (bijective, 512=8*64). Decode clusters
// the LARGER operand per XCD:
//   gemm1   bn-major: each W1T 64-col panel read from exactly 1 XCD's L2
//            (MALL->L2 traffic ~24MB -> ~10MB per eval)
//   gemm2rk4 bm-major: each Hbuf 32-row panel read from exactly 1 XCD's L2
//            (~48MB -> ~20MB per eval)
// Everything else identical to R19:
//   gemm1: 64x64, BK=128, 2 blk/CU, XOR-swizzled 64KB dbuf (R13-proven)
//   gemm2rk4: 32x32 full-K tiles, 4 waves x K-window 512, BK=64, 64KB,
//     fp32 LDS reduce + RK4 epilogue fused (removes combine dispatch)
// Structural notes: 128 dispatch boundaries ~1.6us each are the hardware
// coherence dance (R14-R17 proved software can't beat it). Dispatches: 131.

typedef __bf16 bf16x8 __attribute__((ext_vector_type(8)));
typedef float f32x4 __attribute__((ext_vector_type(4)));

#define AS1 __attribute__((address_space(1)))
#define AS3 __attribute__((address_space(3)))

#define MDIM 1024
#define DDIM 512
#define HDIM 2048

#define GEMM_LDS (64 * 1024)    // gemm1: sA 2x16KB + sB 2x16KB
#define GEMM2_LDS (64 * 1024)   // gemm2rk4: sA 2x16KB + sB 2x16KB (BK=64 x 4 win)

__device__ __forceinline__ void async_copy16(const void* g, void* lds) {
  __builtin_amdgcn_global_load_lds((const AS1 void*)g, (AS3 void*)lds, 16, 0, 0);
}

__device__ __forceinline__ unsigned short f32_to_bf16(float f) {
  union { float f; unsigned u; } c; c.f = f;
  unsigned u = c.u + 0x7FFFu + ((c.u >> 16) & 1u);   // RNE
  return (unsigned short)(u >> 16);
}

__device__ __forceinline__ float tanh_fast(float x) {
  float a = __builtin_fabsf(x);
  float e = __expf(-2.0f * a);                        // in (0,1], no overflow
  float r = (1.0f - e) * __builtin_amdgcn_rcpf(1.0f + e);
  return __builtin_copysignf(r, x);
}

// ---- transpose + f32->bf16: out[c*R + r] = bf16(in[r*C + c]) --------------
__global__ __launch_bounds__(256) void transpose_bf16_kernel(
    const float* __restrict__ in, unsigned short* __restrict__ out, int R, int C) {
  __shared__ float tile[64][65];
  int nbc = C >> 6;
  int br = blockIdx.x / nbc, bc = blockIdx.x % nbc;
  int r0 = br * 64, c0 = bc * 64;
  int tr = threadIdx.x >> 6, tc = threadIdx.x & 63;
  for (int i = 0; i < 16; ++i) {
    int row = i * 4 + tr;
    tile[row][tc] = in[(r0 + row) * C + c0 + tc];
  }
  __syncthreads();
  for (int i = 0; i < 16; ++i) {
    int row = i * 4 + tr;
    out[(c0 + row) * R + r0 + tc] = f32_to_bf16(tile[tc][row]);
  }
}

// ---- init: y = x (fp32, lives in d_out), arg = bf16(x) --------------------
__global__ __launch_bounds__(256) void init_kernel(
    const float* __restrict__ x, float* __restrict__ y,
    unsigned short* __restrict__ arg) {
  int i = blockIdx.x * 256 + threadIdx.x;
  float v = x[i];
  y[i] = v;
  arg[i] = f32_to_bf16(v);
}

// ---- GEMM1: H = tanh(arg[1024,512] @ W1 + b1 + t) -------------------------
// R13-proven core + XCD swizzle (bn-major: W1T panels XCD-local).
__global__ __launch_bounds__(256, 2) void gemm1_kernel(
    const unsigned short* __restrict__ A,    // arg bf16 [1024,512]
    const unsigned short* __restrict__ Bt,   // W1T bf16 [2048,512]
    const float* __restrict__ b1, float tval,
    unsigned short* __restrict__ H)          // [1024,2048] bf16
{
  extern __shared__ char ldsbuf[];
  bf16x8* sA = (bf16x8*)ldsbuf;              // 2 x 1024 units (32KB)
  bf16x8* sB = (bf16x8*)(ldsbuf + 32768);    // 2 x 1024 units (32KB)
  const int K = DDIM;
  const int NITER = 4;            // 512 / 128
  int bid = blockIdx.x;
  int lid = (bid & 7) * 64 + (bid >> 3);   // XCD-contiguous logical id
  int bn = lid >> 4;              // 0..31  (W1T panel: 1 XCD each)
  int bm = lid & 15;              // 0..15
  int tid = threadIdx.x;
  int lane = tid & 63;
  int wid = tid >> 6;
  int l15 = lane & 15;
  int l4 = lane >> 4;
  int wm = (wid >> 1) * 32;
  int wn = (wid & 1) * 32;
  int sw = l15 & 7;               // read-side swizzle (row & 7)

  const unsigned short* gA[4];
  const unsigned short* gB[4];
#pragma unroll
  for (int i = 0; i < 4; ++i) {
    int u = tid + i * 256, r = u >> 4, s = u & 15;
    int koff = ((s ^ (r & 7)) * 8);
    gA[i] = A + (size_t)(bm * 64 + r) * K + koff;
    gB[i] = Bt + (size_t)(bn * 64 + r) * K + koff;
  }
  f32x4 acc[2][2] = {};

#pragma unroll
  for (int i = 0; i < 4; ++i) {
    async_copy16(gA[i], &sA[tid + i * 256]);
    async_copy16(gB[i], &sB[tid + i * 256]);
  }

#pragma unroll 1
  for (int kt = 0; kt < NITER; ++kt) {
    int cur = kt & 1;
    __syncthreads();
    if (kt + 1 < NITER) {
      int nxt = cur ^ 1;
      int off = (kt + 1) * 128;
#pragma unroll
      for (int i = 0; i < 4; ++i) {
        async_copy16(gA[i] + off, &sA[nxt * 1024 + tid + i * 256]);
        async_copy16(gB[i] + off, &sB[nxt * 1024 + tid + i * 256]);
      }
    }
#pragma unroll
    for (int ks = 0; ks < 4; ++ks) {
      int kg = (ks * 4 + l4) ^ sw;
      bf16x8 af[2], bfr[2];
#pragma unroll
      for (int i = 0; i < 2; ++i)
        af[i] = sA[cur * 1024 + (wm + i * 16 + l15) * 16 + kg];
#pragma unroll
      for (int j = 0; j < 2; ++j)
        bfr[j] = sB[cur * 1024 + (wn + j * 16 + l15) * 16 + kg];
#pragma unroll
      for (int i = 0; i < 2; ++i)
#pragma unroll
        for (int j = 0; j < 2; ++j)
          acc[i][j] = __builtin_amdgcn_mfma_f32_16x16x32_bf16(
              af[i], bfr[j], acc[i][j], 0, 0, 0);
    }
  }
  int row0 = bm * 64 + wm + l4 * 4;
  int col0 = bn * 64 + wn + l15;
  float bias[2];
  for (int j = 0; j < 2; ++j) bias[j] = b1[col0 + j * 16] + tval;
#pragma unroll
  for (int i = 0; i < 2; ++i)
#pragma unroll
    for (int r = 0; r < 4; ++r) {
      unsigned short* Hrow = H + (size_t)(row0 + i * 16 + r) * HDIM + col0;
#pragma unroll
      for (int j = 0; j < 2; ++j)
        Hrow[j * 16] = f32_to_bf16(tanh_fast(acc[i][j][r] + bias[j]));
    }
}

// ---- GEMM2 + RK4: k = H @ W2T' + b2, then RK4 state update ----------------
// R19 core + XCD swizzle (bm-major: Hbuf panels XCD-local).
// Tile 32x32, FULL K=2048, 4 waves each own K-window [w*512,+512),
// BK=64 dbuf, fp32 LDS reduce + fused RK4 epilogue.
// mode 0: kacc = k;            arg = bf16(y + dt/2*k)
// mode 1: kacc += 2k;          arg = bf16(y + dt/2*k)
// mode 2: kacc += 2k;          arg = bf16(y + dt*k)
// mode 3: y += dt/6*(kacc+k);  arg = bf16(y_new)
__global__ __launch_bounds__(256, 2) void gemm2rk4_kernel(
    const unsigned short* __restrict__ A,    // H bf16 [1024,2048]
    const unsigned short* __restrict__ Bt,   // W2T bf16 [512,2048]
    const float* __restrict__ b2,
    float* __restrict__ y, float* __restrict__ kacc,
    unsigned short* __restrict__ arg, int mode, float dt)
{
  extern __shared__ char ldsbuf[];
  bf16x8* sA = (bf16x8*)ldsbuf;              // 2 x 1024 units (32KB)
  bf16x8* sB = (bf16x8*)(ldsbuf + 32768);    // 2 x 1024 units (32KB)
  const int K = HDIM;
  int bid = blockIdx.x;
  int lid = (bid & 7) * 64 + (bid >> 3);   // XCD-contiguous logical id
  int bm = lid >> 4;              // 0..31 (Hbuf panel: 1 XCD each)
  int bn = lid & 15;              // 0..15
  int tid = threadIdx.x;
  int lane = tid & 63;
  int wid = tid >> 6;             // wave = K-window 0..3
  int l15 = lane & 15;
  int l4 = lane >> 4;
  int sw = l15 & 7;

  // staging: 1024 units each (4/thread); u -> (win, row, slot)
  const unsigned short* gA[4];
  const unsigned short* gB[4];
#pragma unroll
  for (int i = 0; i < 4; ++i) {
    int u = tid + i * 256;
    int w = u >> 8, r = (u >> 3) & 31, sl = u & 7;
    int koff = w * 512 + ((sl ^ (r & 7)) * 8);
    gA[i] = A  + (size_t)(bm * 32 + r) * K + koff;
    gB[i] = Bt + (size_t)(bn * 32 + r) * K + koff;
  }
  f32x4 acc[2][2] = {};

#pragma unroll
  for (int i = 0; i < 4; ++i) {
    async_copy16(gA[i], &sA[tid + i * 256]);
    async_copy16(gB[i], &sB[tid + i * 256]);
  }

#pragma unroll 1
  for (int kt = 0; kt < 8; ++kt) {
    int cur = kt & 1;
    __syncthreads();
    if (kt + 1 < 8) {
      int nxt = cur ^ 1;
      int off = (kt + 1) * 64;
#pragma unroll
      for (int i = 0; i < 4; ++i) {
        async_copy16(gA[i] + off, &sA[nxt * 1024 + tid + i * 256]);
        async_copy16(gB[i] + off, &sB[nxt * 1024 + tid + i * 256]);
      }
    }
#pragma unroll
    for (int ks = 0; ks < 2; ++ks) {
      int kg = (ks * 4 + l4) ^ sw;
      bf16x8 af[2], bfr[2];
#pragma unroll
      for (int i = 0; i < 2; ++i)
        af[i] = sA[cur * 1024 + wid * 256 + (i * 16 + l15) * 8 + kg];
#pragma unroll
      for (int j = 0; j < 2; ++j)
        bfr[j] = sB[cur * 1024 + wid * 256 + (j * 16 + l15) * 8 + kg];
#pragma unroll
      for (int i = 0; i < 2; ++i)
#pragma unroll
        for (int j = 0; j < 2; ++j)
          acc[i][j] = __builtin_amdgcn_mfma_f32_16x16x32_bf16(
              af[i], bfr[j], acc[i][j], 0, 0, 0);
    }
  }

  // ---- fp32 reduction over the 4 K-windows (overlay on dead staging) ----
  __syncthreads();                         // all staging reads complete
  float* red = (float*)ldsbuf;             // [4][32][36] f32 = 18KB
#pragma unroll
  for (int i = 0; i < 2; ++i)
#pragma unroll
    for (int j = 0; j < 2; ++j)
#pragma unroll
      for (int q = 0; q < 4; ++q) {
        int row = i * 16 + l4 * 4 + q;
        int col = j * 16 + l15;
        red[(wid * 32 + row) * 36 + col] = acc[i][j][q];
      }
  __syncthreads();

  // ---- RK4 epilogue: 256 thr x 4 elems over the 32x32 tile ----
  int row = tid >> 3;                      // 0..31
  int c4 = (tid & 7) * 4;                  // 0..28
  float4 s0 = *(float4*)&red[(0 * 32 + row) * 36 + c4];
  float4 s1 = *(float4*)&red[(1 * 32 + row) * 36 + c4];
  float4 s2 = *(float4*)&red[(2 * 32 + row) * 36 + c4];
  float4 s3 = *(float4*)&red[(3 * 32 + row) * 36 + c4];
  int grow = bm * 32 + row;
  int gcol = bn * 32 + c4;
  size_t off = (size_t)grow * DDIM + gcol;
  float4 bb = *(const float4*)(b2 + gcol);
  float4 k;
  k.x = s0.x + s1.x + s2.x + s3.x + bb.x;
  k.y = s0.y + s1.y + s2.y + s3.y + bb.y;
  k.z = s0.z + s1.z + s2.z + s3.z + bb.z;
  k.w = s0.w + s1.w + s2.w + s3.w + bb.w;
  float4 yv = *(const float4*)(y + off);
  float hh = 0.5f * dt;
  float sx = dt * (1.0f / 6.0f);
  float4 argv;
  if (mode == 0) {
    *(float4*)(kacc + off) = k;
    argv.x = yv.x + hh * k.x; argv.y = yv.y + hh * k.y;
    argv.z = yv.z + hh * k.z; argv.w = yv.w + hh * k.w;
  } else if (mode == 1) {
    float4 ka = *(const float4*)(kacc + off);
    ka.x += 2.0f * k.x; ka.y += 2.0f * k.y; ka.z += 2.0f * k.z; ka.w += 2.0f * k.w;
    *(float4*)(kacc + off) = ka;
    argv.x = yv.x + hh * k.x; argv.y = yv.y + hh * k.y;
    argv.z = yv.z + hh * k.z; argv.w = yv.w + hh * k.w;
  } else if (mode == 2) {
    float4 ka = *(const float4*)(kacc + off);
    ka.x += 2.0f * k.x; ka.y += 2.0f * k.y; ka.z += 2.0f * k.z; ka.w += 2.0f * k.w;
    *(float4*)(kacc + off) = ka;
    argv.x = yv.x + dt * k.x; argv.y = yv.y + dt * k.y;
    argv.z = yv.z + dt * k.z; argv.w = yv.w + dt * k.w;
  } else {
    float4 ka = *(const float4*)(kacc + off);
    argv.x = yv.x + sx * (ka.x + k.x); argv.y = yv.y + sx * (ka.y + k.y);
    argv.z = yv.z + sx * (ka.z + k.z); argv.w = yv.w + sx * (ka.w + k.w);
    *(float4*)(y + off) = argv;
  }
  ushort4 av;
  av.x = f32_to_bf16(argv.x); av.y = f32_to_bf16(argv.y);
  av.z = f32_to_bf16(argv.z); av.w = f32_to_bf16(argv.w);
  *(ushort4*)(arg + off) = av;
}

extern "C" void kernel_launch(void* const* d_in, const int* in_sizes, int n_in,
                              void* d_out, int out_size, void* d_ws, size_t ws_size,
                              hipStream_t stream) {
  (void)in_sizes; (void)n_in; (void)out_size; (void)ws_size;
  const float* x  = (const float*)d_in[0];   // [1024,512]
  const float* W1 = (const float*)d_in[1];   // [512,2048]
  const float* b1 = (const float*)d_in[2];   // [2048]
  const float* W2 = (const float*)d_in[3];   // [2048,512]
  const float* b2 = (const float*)d_in[4];   // [512]
  float* y = (float*)d_out;                  // fp32 state lives in d_out

  char* ws = (char*)d_ws;
  unsigned short* W1T  = (unsigned short*)(ws);                    // 2MB  [2048,512] bf16
  unsigned short* W2T  = (unsigned short*)(ws + (2u << 20));       // 2MB  [512,2048] bf16
  unsigned short* Hbuf = (unsigned short*)(ws + (4u << 20));       // 4MB  [1024,2048] bf16
  unsigned short* arg  = (unsigned short*)(ws + (8u << 20));       // 1MB  [1024,512] bf16
  float*          kacc = (float*)(ws + (9u << 20));                // 2MB  [1024,512] f32

  hipFuncSetAttribute((const void*)gemm1_kernel,
                      hipFuncAttributeMaxDynamicSharedMemorySize, GEMM_LDS);
  hipFuncSetAttribute((const void*)gemm2rk4_kernel,
                      hipFuncAttributeMaxDynamicSharedMemorySize, GEMM2_LDS);

  transpose_bf16_kernel<<<256, 256, 0, stream>>>(W1, W1T, DDIM, HDIM);
  transpose_bf16_kernel<<<256, 256, 0, stream>>>(W2, W2T, HDIM, DDIM);
  init_kernel<<<MDIM * DDIM / 256, 256, 0, stream>>>(x, y, arg);

  const float dt = 1.0f / 16.0f;
  for (int n = 0; n < 16; ++n) {
    float t0 = dt * (float)n;
    const float ts[4] = {t0, t0 + 0.5f * dt, t0 + 0.5f * dt, t0 + dt};
    for (int s = 0; s < 4; ++s) {
      gemm1_kernel<<<512, 256, GEMM_LDS, stream>>>(arg, W1T, b1, ts[s], Hbuf);
      gemm2rk4_kernel<<<512, 256, GEMM2_LDS, stream>>>(Hbuf, W2T, b2, y, kacc, arg, s, dt);
    }
  }
}

// Round 11
// 876.935 us; speedup vs baseline: 5.8364x; 1.2431x over previous
//
#include <hip/hip_runtime.h>
#include <cstdint>

// ODEBlock: 16 RK4 steps of f(t,y) = tanh(y@W1 + b1 + t) @ W2 + b2
// B=1024 (M), D=512, H=2048. gemm1 bf16 MFMA; gemm2 fp8-e4m3 MFMA.
// R23 = R20 (1090us best) + fp8 Hbuf/W2T for gemm2 (staging-BW lever).
// Evidence: gemm2rk4 stages 128MB/eval from L2 (~3.7us at 35TB/s) vs
// ~2.7us MFMA -> staging-bound. fp8 halves bytes, staging insts, barriers
// (BK=128 -> 4 kt), LDS. Non-scaled fp8 MFMA = bf16 rate (m11): no compute
// loss. tanh in (-1,1) is ideal e4m3 range; W2 (+-0.1) fits. Conversion via
// v_cvt_pk_fp8_f32 with duplicated src (byte-order-immune).
// MEGA-KERNEL VERDICT (R14-R17, R21, R22): in-kernel cross-block
// producer->consumer on gfx950 requires full acq/rel L2 wb/inv (R14: correct,
// 4x slow); every per-access protocol (L1-inv / sc0sc1 / sc0 / HW-XCD-id
// ticketing) fails with the identical stale-read absmax 1.9336. Line dead;
// dispatch boundaries are the coherence mechanism. Dispatches: 131.
// Structure (proven): per eval, gemm1 (64x64, BK=128, 2 blk/CU, XOR-swizzle,
// XCD bn-major) -> gemm2rk4 (32x32 full-K, 4 waves x K-window 512, fp8,
// fp32 LDS reduce + fused RK4, XCD bm-major).

typedef __bf16 bf16x8 __attribute__((ext_vector_type(8)));
typedef float f32x4 __attribute__((ext_vector_type(4)));

#define AS1 __attribute__((address_space(1)))
#define AS3 __attribute__((address_space(3)))

#define MDIM 1024
#define DDIM 512
#define HDIM 2048

#define GEMM_LDS (64 * 1024)    // gemm1: sA 2x16KB + sB 2x16KB (bf16)
#define GEMM2_LDS (64 * 1024)   // gemm2rk4: sA8 2x16KB + sB8 2x16KB (fp8)

__device__ __forceinline__ void async_copy16(const void* g, void* lds) {
  __builtin_amdgcn_global_load_lds((const AS1 void*)g, (AS3 void*)lds, 16, 0, 0);
}

__device__ __forceinline__ unsigned short f32_to_bf16(float f) {
  union { float f; unsigned u; } c; c.f = f;
  unsigned u = c.u + 0x7FFFu + ((c.u >> 16) & 1u);   // RNE
  return (unsigned short)(u >> 16);
}

// f32 -> fp8 e4m3 (gfx950 native format); duplicated src so byte order
// of the pack doesn't matter (both bytes identical; take byte 0).
__device__ __forceinline__ unsigned char f32_to_fp8(float v) {
  unsigned p;
  asm("v_cvt_pk_fp8_f32 %0, %1, %1" : "=v"(p) : "v"(v));
  return (unsigned char)(p & 0xFF);
}

__device__ __forceinline__ float tanh_fast(float x) {
  float a = __builtin_fabsf(x);
  float e = __expf(-2.0f * a);                        // in (0,1], no overflow
  float r = (1.0f - e) * __builtin_amdgcn_rcpf(1.0f + e);
  return __builtin_copysignf(r, x);
}

// ---- transpose + f32->bf16: out[c*R + r] = bf16(in[r*C + c]) --------------
__global__ __launch_bounds__(256) void transpose_bf16_kernel(
    const float* __restrict__ in, unsigned short* __restrict__ out, int R, int C) {
  __shared__ float tile[64][65];
  int nbc = C >> 6;
  int br = blockIdx.x / nbc, bc = blockIdx.x % nbc;
  int r0 = br * 64, c0 = bc * 64;
  int tr = threadIdx.x >> 6, tc = threadIdx.x & 63;
  for (int i = 0; i < 16; ++i) {
    int row = i * 4 + tr;
    tile[row][tc] = in[(r0 + row) * C + c0 + tc];
  }
  __syncthreads();
  for (int i = 0; i < 16; ++i) {
    int row = i * 4 + tr;
    out[(c0 + row) * R + r0 + tc] = f32_to_bf16(tile[tc][row]);
  }
}

// ---- transpose + f32->fp8: out[c*R + r] = fp8(in[r*C + c]) ----------------
__global__ __launch_bounds__(256) void transpose_fp8_kernel(
    const float* __restrict__ in, unsigned char* __restrict__ out, int R, int C) {
  __shared__ float tile[64][65];
  int nbc = C >> 6;
  int br = blockIdx.x / nbc, bc = blockIdx.x % nbc;
  int r0 = br * 64, c0 = bc * 64;
  int tr = threadIdx.x >> 6, tc = threadIdx.x & 63;
  for (int i = 0; i < 16; ++i) {
    int row = i * 4 + tr;
    tile[row][tc] = in[(r0 + row) * C + c0 + tc];
  }
  __syncthreads();
  for (int i = 0; i < 16; ++i) {
    int row = i * 4 + tr;
    out[(c0 + row) * R + r0 + tc] = f32_to_fp8(tile[tc][row]);
  }
}

// ---- init: y = x (fp32, lives in d_out), arg = bf16(x) --------------------
__global__ __launch_bounds__(256) void init_kernel(
    const float* __restrict__ x, float* __restrict__ y,
    unsigned short* __restrict__ arg) {
  int i = blockIdx.x * 256 + threadIdx.x;
  float v = x[i];
  y[i] = v;
  arg[i] = f32_to_bf16(v);
}

// ---- GEMM1: H = fp8(tanh(arg[1024,512] @ W1 + b1 + t)) --------------------
// R13-proven bf16 core + XCD swizzle (bn-major) + fp8 H epilogue.
__global__ __launch_bounds__(256, 2) void gemm1_kernel(
    const unsigned short* __restrict__ A,    // arg bf16 [1024,512]
    const unsigned short* __restrict__ Bt,   // W1T bf16 [2048,512]
    const float* __restrict__ b1, float tval,
    unsigned char* __restrict__ H8)          // [1024,2048] fp8
{
  extern __shared__ char ldsbuf[];
  bf16x8* sA = (bf16x8*)ldsbuf;              // 2 x 1024 units (32KB)
  bf16x8* sB = (bf16x8*)(ldsbuf + 32768);    // 2 x 1024 units (32KB)
  const int K = DDIM;
  const int NITER = 4;            // 512 / 128
  int bid = blockIdx.x;
  int lid = (bid & 7) * 64 + (bid >> 3);   // XCD-contiguous logical id
  int bn = lid >> 4;              // 0..31  (W1T panel: 1 XCD each)
  int bm = lid & 15;              // 0..15
  int tid = threadIdx.x;
  int lane = tid & 63;
  int wid = tid >> 6;
  int l15 = lane & 15;
  int l4 = lane >> 4;
  int wm = (wid >> 1) * 32;
  int wn = (wid & 1) * 32;
  int sw = l15 & 7;               // read-side swizzle (row & 7)

  const unsigned short* gA[4];
  const unsigned short* gB[4];
#pragma unroll
  for (int i = 0; i < 4; ++i) {
    int u = tid + i * 256, r = u >> 4, s = u & 15;
    int koff = ((s ^ (r & 7)) * 8);
    gA[i] = A + (size_t)(bm * 64 + r) * K + koff;
    gB[i] = Bt + (size_t)(bn * 64 + r) * K + koff;
  }
  f32x4 acc[2][2] = {};

#pragma unroll
  for (int i = 0; i < 4; ++i) {
    async_copy16(gA[i], &sA[tid + i * 256]);
    async_copy16(gB[i], &sB[tid + i * 256]);
  }

#pragma unroll 1
  for (int kt = 0; kt < NITER; ++kt) {
    int cur = kt & 1;
    __syncthreads();
    if (kt + 1 < NITER) {
      int nxt = cur ^ 1;
      int off = (kt + 1) * 128;
#pragma unroll
      for (int i = 0; i < 4; ++i) {
        async_copy16(gA[i] + off, &sA[nxt * 1024 + tid + i * 256]);
        async_copy16(gB[i] + off, &sB[nxt * 1024 + tid + i * 256]);
      }
    }
#pragma unroll
    for (int ks = 0; ks < 4; ++ks) {
      int kg = (ks * 4 + l4) ^ sw;
      bf16x8 af[2], bfr[2];
#pragma unroll
      for (int i = 0; i < 2; ++i)
        af[i] = sA[cur * 1024 + (wm + i * 16 + l15) * 16 + kg];
#pragma unroll
      for (int j = 0; j < 2; ++j)
        bfr[j] = sB[cur * 1024 + (wn + j * 16 + l15) * 16 + kg];
#pragma unroll
      for (int i = 0; i < 2; ++i)
#pragma unroll
        for (int j = 0; j < 2; ++j)
          acc[i][j] = __builtin_amdgcn_mfma_f32_16x16x32_bf16(
              af[i], bfr[j], acc[i][j], 0, 0, 0);
    }
  }
  int row0 = bm * 64 + wm + l4 * 4;
  int col0 = bn * 64 + wn + l15;
  float bias[2];
  for (int j = 0; j < 2; ++j) bias[j] = b1[col0 + j * 16] + tval;
#pragma unroll
  for (int i = 0; i < 2; ++i)
#pragma unroll
    for (int r = 0; r < 4; ++r) {
      unsigned char* Hrow = H8 + (size_t)(row0 + i * 16 + r) * HDIM + col0;
      Hrow[0]  = f32_to_fp8(tanh_fast(acc[i][0][r] + bias[0]));
      Hrow[16] = f32_to_fp8(tanh_fast(acc[i][1][r] + bias[1]));
    }
}

// ---- GEMM2 (fp8) + RK4: k = H @ W2T' + b2, then RK4 state update ----------
// Tile 32x32, FULL K=2048, fp8 operands. Grid 32x16 = 512, 256 thr.
// Wave w owns K-window [w*512,+512): 4 kt of BK=128 (fp8: 128B rows),
// 4 ks of K=32 fp8-MFMA each, acc 2x2 frags. LDS unit = 16B = 16 fp8;
// unit u -> (win=u>>8, r=(u>>3)&31, slot16=u&7), XOR swizzle slot^(r&7).
// Reads: ds_read_b64 (8 fp8 = one MFMA operand). fp32 reduce over 4
// windows in 18KB overlay + fused RK4 epilogue (same as R20).
// mode 0: kacc = k;            arg = bf16(y + dt/2*k)
// mode 1: kacc += 2k;          arg = bf16(y + dt/2*k)
// mode 2: kacc += 2k;          arg = bf16(y + dt*k)
// mode 3: y += dt/6*(kacc+k);  arg = bf16(y_new)
__global__ __launch_bounds__(256, 2) void gemm2rk4_kernel(
    const unsigned char* __restrict__ A8,    // H fp8 [1024,2048]
    const unsigned char* __restrict__ B8,    // W2T fp8 [512,2048]
    const float* __restrict__ b2,
    float* __restrict__ y, float* __restrict__ kacc,
    unsigned short* __restrict__ arg, int mode, float dt)
{
  extern __shared__ char ldsbuf[];
  char* sA8 = ldsbuf;              // 2 x 16KB
  char* sB8 = ldsbuf + 32768;      // 2 x 16KB
  const int K = HDIM;
  int bid = blockIdx.x;
  int lid = (bid & 7) * 64 + (bid >> 3);   // XCD-contiguous logical id
  int bm = lid >> 4;              // 0..31 (Hbuf panel: 1 XCD each)
  int bn = lid & 15;              // 0..15
  int tid = threadIdx.x;
  int lane = tid & 63;
  int wid = tid >> 6;             // wave = K-window 0..3
  int l15 = lane & 15;
  int l4 = lane >> 4;
  int sw = l15 & 7;

  // staging: 1024 16B-units per matrix per kt (4/thread)
  // unit u -> (win=u>>8, row=(u>>3)&31, slot16=u&7); row = 128B (BK=128 fp8)
  const unsigned char* gA[4];
  const unsigned char* gB[4];
#pragma unroll
  for (int i = 0; i < 4; ++i) {
    int u = tid + i * 256;
    int w = u >> 8, r = (u >> 3) & 31, sl = u & 7;
    int koff = w * 512 + ((sl ^ (r & 7)) * 16);
    gA[i] = A8 + (size_t)(bm * 32 + r) * K + koff;
    gB[i] = B8 + (size_t)(bn * 32 + r) * K + koff;
  }
  f32x4 acc[2][2] = {};

#pragma unroll
  for (int i = 0; i < 4; ++i) {
    async_copy16(gA[i], sA8 + (tid + i * 256) * 16);
    async_copy16(gB[i], sB8 + (tid + i * 256) * 16);
  }

#pragma unroll 1
  for (int kt = 0; kt < 4; ++kt) {
    int cur = kt & 1;
    __syncthreads();
    if (kt + 1 < 4) {
      int nxt = cur ^ 1;
      int off = (kt + 1) * 128;            // 128 fp8 = 128 B
#pragma unroll
      for (int i = 0; i < 4; ++i) {
        async_copy16(gA[i] + off, sA8 + nxt * 16384 + (tid + i * 256) * 16);
        async_copy16(gB[i] + off, sB8 + nxt * 16384 + (tid + i * 256) * 16);
      }
    }
#pragma unroll
    for (int ks = 0; ks < 4; ++ks) {
      // lane wants k-bytes [ks*32 + l4*8, +8) of its window's 128B row:
      // 16B-slot c = ks*2 + (l4>>1) (XOR-swizzled), +8B if l4 odd.
      int soff = (((ks * 2 + (l4 >> 1)) ^ sw) * 16) + (l4 & 1) * 8;
      long af[2], bfr[2];
#pragma unroll
      for (int i = 0; i < 2; ++i)
        af[i] = *(const long*)(sA8 + cur * 16384 + wid * 4096 +
                               (i * 16 + l15) * 128 + soff);
#pragma unroll
      for (int j = 0; j < 2; ++j)
        bfr[j] = *(const long*)(sB8 + cur * 16384 + wid * 4096 +
                                (j * 16 + l15) * 128 + soff);
#pragma unroll
      for (int i = 0; i < 2; ++i)
#pragma unroll
        for (int j = 0; j < 2; ++j)
          acc[i][j] = __builtin_amdgcn_mfma_f32_16x16x32_fp8_fp8(
              af[i], bfr[j], acc[i][j], 0, 0, 0);
    }
  }

  // ---- fp32 reduction over the 4 K-windows (overlay on dead staging) ----
  __syncthreads();                         // all staging reads complete
  float* red = (float*)ldsbuf;             // [4][32][36] f32 = 18KB
#pragma unroll
  for (int i = 0; i < 2; ++i)
#pragma unroll
    for (int j = 0; j < 2; ++j)
#pragma unroll
      for (int q = 0; q < 4; ++q) {
        int row = i * 16 + l4 * 4 + q;
        int col = j * 16 + l15;
        red[(wid * 32 + row) * 36 + col] = acc[i][j][q];
      }
  __syncthreads();

  // ---- RK4 epilogue: 256 thr x 4 elems over the 32x32 tile ----
  int row = tid >> 3;                      // 0..31
  int c4 = (tid & 7) * 4;                  // 0..28
  float4 s0 = *(float4*)&red[(0 * 32 + row) * 36 + c4];
  float4 s1 = *(float4*)&red[(1 * 32 + row) * 36 + c4];
  float4 s2 = *(float4*)&red[(2 * 32 + row) * 36 + c4];
  float4 s3 = *(float4*)&red[(3 * 32 + row) * 36 + c4];
  int grow = bm * 32 + row;
  int gcol = bn * 32 + c4;
  size_t off = (size_t)grow * DDIM + gcol;
  float4 bb = *(const float4*)(b2 + gcol);
  float4 k;
  k.x = s0.x + s1.x + s2.x + s3.x + bb.x;
  k.y = s0.y + s1.y + s2.y + s3.y + bb.y;
  k.z = s0.z + s1.z + s2.z + s3.z + bb.z;
  k.w = s0.w + s1.w + s2.w + s3.w + bb.w;
  float4 yv = *(const float4*)(y + off);
  float hh = 0.5f * dt;
  float sx = dt * (1.0f / 6.0f);
  float4 argv;
  if (mode == 0) {
    *(float4*)(kacc + off) = k;
    argv.x = yv.x + hh * k.x; argv.y = yv.y + hh * k.y;
    argv.z = yv.z + hh * k.z; argv.w = yv.w + hh * k.w;
  } else if (mode == 1) {
    float4 ka = *(const float4*)(kacc + off);
    ka.x += 2.0f * k.x; ka.y += 2.0f * k.y; ka.z += 2.0f * k.z; ka.w += 2.0f * k.w;
    *(float4*)(kacc + off) = ka;
    argv.x = yv.x + hh * k.x; argv.y = yv.y + hh * k.y;
    argv.z = yv.z + hh * k.z; argv.w = yv.w + hh * k.w;
  } else if (mode == 2) {
    float4 ka = *(const float4*)(kacc + off);
    ka.x += 2.0f * k.x; ka.y += 2.0f * k.y; ka.z += 2.0f * k.z; ka.w += 2.0f * k.w;
    *(float4*)(kacc + off) = ka;
    argv.x = yv.x + dt * k.x; argv.y = yv.y + dt * k.y;
    argv.z = yv.z + dt * k.z; argv.w = yv.w + dt * k.w;
  } else {
    float4 ka = *(const float4*)(kacc + off);
    argv.x = yv.x + sx * (ka.x + k.x); argv.y = yv.y + sx * (ka.y + k.y);
    argv.z = yv.z + sx * (ka.z + k.z); argv.w = yv.w + sx * (ka.w + k.w);
    *(float4*)(y + off) = argv;
  }
  ushort4 av;
  av.x = f32_to_bf16(argv.x); av.y = f32_to_bf16(argv.y);
  av.z = f32_to_bf16(argv.z); av.w = f32_to_bf16(argv.w);
  *(ushort4*)(arg + off) = av;
}

extern "C" void kernel_launch(void* const* d_in, const int* in_sizes, int n_in,
                              void* d_out, int out_size, void* d_ws, size_t ws_size,
                              hipStream_t stream) {
  (void)in_sizes; (void)n_in; (void)out_size; (void)ws_size;
  const float* x  = (const float*)d_in[0];   // [1024,512]
  const float* W1 = (const float*)d_in[1];   // [512,2048]
  const float* b1 = (const float*)d_in[2];   // [2048]
  const float* W2 = (const float*)d_in[3];   // [2048,512]
  const float* b2 = (const float*)d_in[4];   // [512]
  float* y = (float*)d_out;                  // fp32 state lives in d_out

  char* ws = (char*)d_ws;
  unsigned short* W1T  = (unsigned short*)(ws);                    // 2MB  [2048,512] bf16
  unsigned char*  W2T8 = (unsigned char*)(ws + (2u << 20));        // 1MB  [512,2048] fp8
  unsigned char*  H8   = (unsigned char*)(ws + (4u << 20));        // 2MB  [1024,2048] fp8
  unsigned short* arg  = (unsigned short*)(ws + (8u << 20));       // 1MB  [1024,512] bf16
  float*          kacc = (float*)(ws + (9u << 20));                // 2MB  [1024,512] f32

  hipFuncSetAttribute((const void*)gemm1_kernel,
                      hipFuncAttributeMaxDynamicSharedMemorySize, GEMM_LDS);
  hipFuncSetAttribute((const void*)gemm2rk4_kernel,
                      hipFuncAttributeMaxDynamicSharedMemorySize, GEMM2_LDS);

  transpose_bf16_kernel<<<256, 256, 0, stream>>>(W1, W1T, DDIM, HDIM);
  transpose_fp8_kernel<<<256, 256, 0, stream>>>(W2, W2T8, HDIM, DDIM);
  init_kernel<<<MDIM * DDIM / 256, 256, 0, stream>>>(x, y, arg);

  const float dt = 1.0f / 16.0f;
  for (int n = 0; n < 16; ++n) {
    float t0 = dt * (float)n;
    const float ts[4] = {t0, t0 + 0.5f * dt, t0 + 0.5f * dt, t0 + dt};
    for (int s = 0; s < 4; ++s) {
      gemm1_kernel<<<512, 256, GEMM_LDS, stream>>>(arg, W1T, b1, ts[s], H8);
      gemm2rk4_kernel<<<512, 256, GEMM2_LDS, stream>>>(H8, W2T8, b2, y, kacc, arg, s, dt);
    }
  }
}